// Round 1
// baseline (2409.648 us; speedup 1.0000x reference)
//
#include <hip/hip_runtime.h>

#define NN 100000
#define DD 128
#define EE 640000
#define BN_EPS 1e-3f

typedef __bf16 bf16x8 __attribute__((ext_vector_type(8)));
typedef float f32x4 __attribute__((ext_vector_type(4)));

// ---- workspace byte offsets ----
#define W1F_OFF 0u            // 128x128 bf16 frags    = 32768 B
#define W2F_OFF 32768u        // 256x128 bf16 frags    = 65536 B
#define B1F_OFF 98304u        // 128 f32
#define B2F_OFF 98816u        // 128 f32
#define T_OFF   99328u        // NN*128 bf16           = 25,600,000 B
#define SUMS_OFF 25699328u    // NN*128 f32            = 51,200,000 B
#define CNT_OFF  76899328u    // NN f32                = 400,000 B

__device__ __forceinline__ float gelu_exact(float x) {
    return 0.5f * x * (1.0f + erff(x * 0.70710678118654752f));
}

// Fold BN into weights; write W in MFMA B-fragment order (bf16).
// B-frag layout for 16x16x32: lane l holds B[k=(l>>4)*8+i][n=(l&15)], per (ktile,ntile).
// linear idx -> i = idx&7, l = (idx>>3)&63, nt = (idx>>9)&7, kt = idx>>12
// agg-half rows of W2 are permuted to match ffn1's permuted t layout:
// physical col' p -> logical col (p&7)*16 + (p>>3)
__global__ void fold_kernel(
    const float* __restrict__ g1, const float* __restrict__ be1,
    const float* __restrict__ m1, const float* __restrict__ v1,
    const float* __restrict__ W1, const float* __restrict__ b1,
    const float* __restrict__ g2, const float* __restrict__ be2,
    const float* __restrict__ m2, const float* __restrict__ v2,
    const float* __restrict__ W2, const float* __restrict__ b2,
    __bf16* __restrict__ W1f, __bf16* __restrict__ W2f,
    float* __restrict__ b1f, float* __restrict__ b2f)
{
    const int tid = threadIdx.x;
    if (tid < 128) {
        float acc = b1[tid];
        for (int k = 0; k < 128; ++k) {
            float s = g1[k] * rsqrtf(v1[k] + BN_EPS);
            float sh = be1[k] - m1[k] * s;
            acc += sh * W1[k * 128 + tid];
        }
        b1f[tid] = acc;
        float acc2 = b2[tid];
        for (int k = 0; k < 256; ++k) {
            float s = g2[k] * rsqrtf(v2[k] + BN_EPS);
            float sh = be2[k] - m2[k] * s;
            acc2 += sh * W2[k * 128 + tid];
        }
        b2f[tid] = acc2;
    }
    for (int idx = tid; idx < 16384; idx += 256) {
        int i = idx & 7, l = (idx >> 3) & 63, nt = (idx >> 9) & 7, kt = idx >> 12;
        int k = kt * 32 + (l >> 4) * 8 + i;
        int n = nt * 16 + (l & 15);
        float s = g1[k] * rsqrtf(v1[k] + BN_EPS);
        W1f[idx] = (__bf16)(s * W1[k * 128 + n]);
    }
    for (int idx = tid; idx < 32768; idx += 256) {
        int i = idx & 7, l = (idx >> 3) & 63, nt = (idx >> 9) & 7, kt = idx >> 12;
        int n = nt * 16 + (l & 15);
        int row;
        if (kt < 4) {
            row = kt * 32 + (l >> 4) * 8 + i;
        } else {
            int q = (kt - 4) * 32 + (l >> 4) * 8 + i;      // physical agg col
            row = 128 + ((q & 7) * 16 + (q >> 3));          // logical W2 row
        }
        float s = g2[row] * rsqrtf(v2[row] + BN_EPS);
        W2f[idx] = (__bf16)(s * W2[row * 128 + n]);
    }
}

// t = gelu(X @ W1f + b1f), stored bf16 with permuted cols: col' = (col&15)*8 + (col>>4)
__global__ __launch_bounds__(256) void ffn1_kernel(
    const float* __restrict__ X, const __bf16* __restrict__ W1f,
    const float* __restrict__ b1f, __bf16* __restrict__ T)
{
    const int wave = threadIdx.x >> 6;
    const int lane = threadIdx.x & 63;
    const int c = lane & 15, kh = lane >> 4;
    const int rowbase = (blockIdx.x * 4 + wave) * 16;

    int rowA = rowbase + c;
    if (rowA >= NN) rowA = NN - 1;
    const float* xr = X + (size_t)rowA * DD + kh * 8;

    bf16x8 afrag[4];
#pragma unroll
    for (int kt = 0; kt < 4; ++kt) {
        f32x4 a0 = *(const f32x4*)(xr + kt * 32);
        f32x4 a1 = *(const f32x4*)(xr + kt * 32 + 4);
        bf16x8 af;
#pragma unroll
        for (int i = 0; i < 4; ++i) { af[i] = (__bf16)a0[i]; af[4 + i] = (__bf16)a1[i]; }
        afrag[kt] = af;
    }

    f32x4 acc[8] = {};
#pragma unroll
    for (int kt = 0; kt < 4; ++kt)
#pragma unroll
        for (int nt = 0; nt < 8; ++nt) {
            bf16x8 bfr = *(const bf16x8*)(W1f + ((size_t)((kt * 8 + nt) * 64 + lane)) * 8);
            acc[nt] = __builtin_amdgcn_mfma_f32_16x16x32_bf16(afrag[kt], bfr, acc[nt], 0, 0, 0);
        }

    float bias[8];
#pragma unroll
    for (int nt = 0; nt < 8; ++nt) bias[nt] = b1f[nt * 16 + c];

#pragma unroll
    for (int r = 0; r < 4; ++r) {
        int row = rowbase + kh * 4 + r;
        if (row < NN) {
            bf16x8 o;
#pragma unroll
            for (int nt = 0; nt < 8; ++nt)
                o[nt] = (__bf16)gelu_exact(acc[nt][r] + bias[nt]);
            *(bf16x8*)(T + (size_t)row * DD + c * 8) = o;
        }
    }
}

// sums[dst] += t[src]; cnt[dst] += 1.  16 threads per edge, 8 dims each.
__global__ __launch_bounds__(256) void scatter_kernel(
    const int* __restrict__ edges, const __bf16* __restrict__ T,
    float* __restrict__ sums, float* __restrict__ cnt)
{
    int t = blockIdx.x * 256 + threadIdx.x;
    int e = t >> 4, j = t & 15;
    if (e >= EE) return;
    int dst = edges[e];
    int src = edges[EE + e];
    bf16x8 v = *(const bf16x8*)(T + (size_t)src * DD + j * 8);
    float* sp = sums + (size_t)dst * DD + j * 8;
#pragma unroll
    for (int i = 0; i < 8; ++i)
        unsafeAtomicAdd(sp + i, (float)v[i]);
    if (j == 0) unsafeAtomicAdd(cnt + dst, 1.0f);
}

// out = gelu([X, sums/max(cnt,1)] @ W2f + b2f)
__global__ __launch_bounds__(256) void ffn2_kernel(
    const float* __restrict__ X, const float* __restrict__ sums,
    const float* __restrict__ cnt, const __bf16* __restrict__ W2f,
    const float* __restrict__ b2f, float* __restrict__ out)
{
    const int wave = threadIdx.x >> 6;
    const int lane = threadIdx.x & 63;
    const int c = lane & 15, kh = lane >> 4;
    const int rowbase = (blockIdx.x * 4 + wave) * 16;

    int rowA = rowbase + c;
    if (rowA >= NN) rowA = NN - 1;
    const float* xr = X + (size_t)rowA * DD + kh * 8;
    const float* sr = sums + (size_t)rowA * DD + kh * 8;
    const float inv = 1.0f / fmaxf(cnt[rowA], 1.0f);

    bf16x8 afrag[8];
#pragma unroll
    for (int kt = 0; kt < 4; ++kt) {
        f32x4 a0 = *(const f32x4*)(xr + kt * 32);
        f32x4 a1 = *(const f32x4*)(xr + kt * 32 + 4);
        bf16x8 af;
#pragma unroll
        for (int i = 0; i < 4; ++i) { af[i] = (__bf16)a0[i]; af[4 + i] = (__bf16)a1[i]; }
        afrag[kt] = af;
    }
#pragma unroll
    for (int kt = 0; kt < 4; ++kt) {
        f32x4 a0 = *(const f32x4*)(sr + kt * 32);
        f32x4 a1 = *(const f32x4*)(sr + kt * 32 + 4);
        bf16x8 af;
#pragma unroll
        for (int i = 0; i < 4; ++i) { af[i] = (__bf16)(a0[i] * inv); af[4 + i] = (__bf16)(a1[i] * inv); }
        afrag[4 + kt] = af;
    }

    f32x4 acc[8] = {};
#pragma unroll
    for (int kt = 0; kt < 8; ++kt)
#pragma unroll
        for (int nt = 0; nt < 8; ++nt) {
            bf16x8 bfr = *(const bf16x8*)(W2f + ((size_t)((kt * 8 + nt) * 64 + lane)) * 8);
            acc[nt] = __builtin_amdgcn_mfma_f32_16x16x32_bf16(afrag[kt], bfr, acc[nt], 0, 0, 0);
        }

    float bias[8];
#pragma unroll
    for (int nt = 0; nt < 8; ++nt) bias[nt] = b2f[nt * 16 + c];

#pragma unroll
    for (int r = 0; r < 4; ++r) {
        int row = rowbase + kh * 4 + r;
        if (row < NN) {
#pragma unroll
            for (int nt = 0; nt < 8; ++nt)
                out[(size_t)row * DD + nt * 16 + c] = gelu_exact(acc[nt][r] + bias[nt]);
        }
    }
}

extern "C" void kernel_launch(void* const* d_in, const int* in_sizes, int n_in,
                              void* d_out, int out_size, void* d_ws, size_t ws_size,
                              hipStream_t stream) {
    const float* node_repr = (const float*)d_in[0];
    const int*   edges     = (const int*)d_in[1];
    const float* g1 = (const float*)d_in[2];
    const float* be1 = (const float*)d_in[3];
    const float* m1 = (const float*)d_in[4];
    const float* v1 = (const float*)d_in[5];
    const float* W1 = (const float*)d_in[6];
    const float* b1 = (const float*)d_in[7];
    const float* g2 = (const float*)d_in[8];
    const float* be2 = (const float*)d_in[9];
    const float* m2 = (const float*)d_in[10];
    const float* v2 = (const float*)d_in[11];
    const float* W2 = (const float*)d_in[12];
    const float* b2 = (const float*)d_in[13];

    char* ws = (char*)d_ws;
    __bf16* W1f = (__bf16*)(ws + W1F_OFF);
    __bf16* W2f = (__bf16*)(ws + W2F_OFF);
    float* b1f = (float*)(ws + B1F_OFF);
    float* b2f = (float*)(ws + B2F_OFF);
    __bf16* T  = (__bf16*)(ws + T_OFF);
    float* sums = (float*)(ws + SUMS_OFF);
    float* cnt  = (float*)(ws + CNT_OFF);
    float* out = (float*)d_out;

    hipMemsetAsync(sums, 0, (size_t)NN * DD * 4 + (size_t)NN * 4, stream);

    hipLaunchKernelGGL(fold_kernel, dim3(1), dim3(256), 0, stream,
                       g1, be1, m1, v1, W1, b1, g2, be2, m2, v2, W2, b2,
                       W1f, W2f, b1f, b2f);

    hipLaunchKernelGGL(ffn1_kernel, dim3((NN + 63) / 64), dim3(256), 0, stream,
                       node_repr, W1f, b1f, T);

    hipLaunchKernelGGL(scatter_kernel, dim3((EE * 16) / 256), dim3(256), 0, stream,
                       edges, T, sums, cnt);

    hipLaunchKernelGGL(ffn2_kernel, dim3((NN + 63) / 64), dim3(256), 0, stream,
                       node_repr, sums, cnt, W2f, b2f, out);
}

// Round 2
// 495.300 us; speedup vs baseline: 4.8650x; 4.8650x over previous
//
#include <hip/hip_runtime.h>

#define NN 100000
#define DD 128
#define EE 640000
#define BN_EPS 1e-3f

typedef __bf16 bf16x8 __attribute__((ext_vector_type(8)));
typedef float f32x4 __attribute__((ext_vector_type(4)));

// ---- workspace byte offsets ----
#define W1F_OFF 0u            // 128x128 bf16 frags    = 32768 B
#define W2F_OFF 32768u        // 256x128 bf16 frags    = 65536 B
#define B1F_OFF 98304u        // 128 f32
#define B2F_OFF 98816u        // 128 f32
#define T_OFF   99328u        // NN*128 bf16           = 25,600,000 B
#define DEG_OFF 25699328u     // NN int
#define OFFS_OFF 26099328u    // NN int
#define CUR_OFF 26499328u     // NN int
#define ELIST_OFF 26899328u   // EE int = 2,560,000 B  (end 29,459,328)

__device__ __forceinline__ float gelu_exact(float x) {
    return 0.5f * x * (1.0f + erff(x * 0.70710678118654752f));
}

// Fold BN into weights; write W in MFMA B-fragment order (bf16).
// B-frag layout for 16x16x32: lane l holds B[k=(l>>4)*8+i][n=(l&15)], per (ktile,ntile).
// linear idx -> i = idx&7, l = (idx>>3)&63, nt = (idx>>9)&7, kt = idx>>12
// agg-half rows of W2 are permuted to match ffn1's permuted t layout:
// physical col' p -> logical col (p&7)*16 + (p>>3)
__global__ void fold_kernel(
    const float* __restrict__ g1, const float* __restrict__ be1,
    const float* __restrict__ m1, const float* __restrict__ v1,
    const float* __restrict__ W1, const float* __restrict__ b1,
    const float* __restrict__ g2, const float* __restrict__ be2,
    const float* __restrict__ m2, const float* __restrict__ v2,
    const float* __restrict__ W2, const float* __restrict__ b2,
    __bf16* __restrict__ W1f, __bf16* __restrict__ W2f,
    float* __restrict__ b1f, float* __restrict__ b2f)
{
    const int tid = threadIdx.x;
    if (tid < 128) {
        float acc = b1[tid];
        for (int k = 0; k < 128; ++k) {
            float s = g1[k] * rsqrtf(v1[k] + BN_EPS);
            float sh = be1[k] - m1[k] * s;
            acc += sh * W1[k * 128 + tid];
        }
        b1f[tid] = acc;
        float acc2 = b2[tid];
        for (int k = 0; k < 256; ++k) {
            float s = g2[k] * rsqrtf(v2[k] + BN_EPS);
            float sh = be2[k] - m2[k] * s;
            acc2 += sh * W2[k * 128 + tid];
        }
        b2f[tid] = acc2;
    }
    for (int idx = tid; idx < 16384; idx += 256) {
        int i = idx & 7, l = (idx >> 3) & 63, nt = (idx >> 9) & 7, kt = idx >> 12;
        int k = kt * 32 + (l >> 4) * 8 + i;
        int n = nt * 16 + (l & 15);
        float s = g1[k] * rsqrtf(v1[k] + BN_EPS);
        W1f[idx] = (__bf16)(s * W1[k * 128 + n]);
    }
    for (int idx = tid; idx < 32768; idx += 256) {
        int i = idx & 7, l = (idx >> 3) & 63, nt = (idx >> 9) & 7, kt = idx >> 12;
        int n = nt * 16 + (l & 15);
        int row;
        if (kt < 4) {
            row = kt * 32 + (l >> 4) * 8 + i;
        } else {
            int q = (kt - 4) * 32 + (l >> 4) * 8 + i;      // physical agg col
            row = 128 + ((q & 7) * 16 + (q >> 3));          // logical W2 row
        }
        float s = g2[row] * rsqrtf(v2[row] + BN_EPS);
        W2f[idx] = (__bf16)(s * W2[row * 128 + n]);
    }
}

// t = gelu(X @ W1f + b1f), stored bf16 with permuted cols: col' = (col&15)*8 + (col>>4)
__global__ __launch_bounds__(256) void ffn1_kernel(
    const float* __restrict__ X, const __bf16* __restrict__ W1f,
    const float* __restrict__ b1f, __bf16* __restrict__ T)
{
    const int wave = threadIdx.x >> 6;
    const int lane = threadIdx.x & 63;
    const int c = lane & 15, kh = lane >> 4;
    const int rowbase = (blockIdx.x * 4 + wave) * 16;

    int rowA = rowbase + c;
    if (rowA >= NN) rowA = NN - 1;
    const float* xr = X + (size_t)rowA * DD + kh * 8;

    bf16x8 afrag[4];
#pragma unroll
    for (int kt = 0; kt < 4; ++kt) {
        f32x4 a0 = *(const f32x4*)(xr + kt * 32);
        f32x4 a1 = *(const f32x4*)(xr + kt * 32 + 4);
        bf16x8 af;
#pragma unroll
        for (int i = 0; i < 4; ++i) { af[i] = (__bf16)a0[i]; af[4 + i] = (__bf16)a1[i]; }
        afrag[kt] = af;
    }

    f32x4 acc[8] = {};
#pragma unroll
    for (int kt = 0; kt < 4; ++kt)
#pragma unroll
        for (int nt = 0; nt < 8; ++nt) {
            bf16x8 bfr = *(const bf16x8*)(W1f + ((size_t)((kt * 8 + nt) * 64 + lane)) * 8);
            acc[nt] = __builtin_amdgcn_mfma_f32_16x16x32_bf16(afrag[kt], bfr, acc[nt], 0, 0, 0);
        }

    float bias[8];
#pragma unroll
    for (int nt = 0; nt < 8; ++nt) bias[nt] = b1f[nt * 16 + c];

#pragma unroll
    for (int r = 0; r < 4; ++r) {
        int row = rowbase + kh * 4 + r;
        if (row < NN) {
            bf16x8 o;
#pragma unroll
            for (int nt = 0; nt < 8; ++nt)
                o[nt] = (__bf16)gelu_exact(acc[nt][r] + bias[nt]);
            *(bf16x8*)(T + (size_t)row * DD + c * 8) = o;
        }
    }
}

// deg[dst]++ over all edges
__global__ __launch_bounds__(256) void hist_kernel(const int* __restrict__ edges,
                                                   int* __restrict__ deg)
{
    int e = blockIdx.x * 256 + threadIdx.x;
    if (e < EE) atomicAdd(&deg[edges[e]], 1);
}

// single-block exclusive scan of deg -> offs, cursor
__global__ __launch_bounds__(1024) void scan_kernel(const int* __restrict__ deg,
                                                    int* __restrict__ offs,
                                                    int* __restrict__ cursor)
{
    __shared__ int part[1024];
    const int t = threadIdx.x;
    const int CH = (NN + 1023) / 1024;   // 98
    const int base = t * CH;
    int s = 0;
    for (int i = 0; i < CH; ++i) {
        int idx = base + i;
        if (idx < NN) s += deg[idx];
    }
    part[t] = s;
    __syncthreads();
    for (int off = 1; off < 1024; off <<= 1) {
        int tmp = (t >= off) ? part[t - off] : 0;
        __syncthreads();
        part[t] += tmp;
        __syncthreads();
    }
    int run = part[t] - s;   // exclusive prefix of this chunk
    for (int i = 0; i < CH; ++i) {
        int idx = base + i;
        if (idx < NN) {
            offs[idx] = run;
            cursor[idx] = run;
            run += deg[idx];
        }
    }
}

// CSR edge list: elist[offs[dst] ...] = src
__global__ __launch_bounds__(256) void build_kernel(const int* __restrict__ edges,
                                                    int* __restrict__ cursor,
                                                    int* __restrict__ elist)
{
    int e = blockIdx.x * 256 + threadIdx.x;
    if (e >= EE) return;
    int dst = edges[e];
    int src = edges[EE + e];
    int pos = atomicAdd(&cursor[dst], 1);
    elist[pos] = src;
}

// out = gelu([X, mean_gather(T)] @ W2f + b2f); aggregation fused via CSR gather
__global__ __launch_bounds__(256) void ffn2_kernel(
    const float* __restrict__ X, const __bf16* __restrict__ T,
    const int* __restrict__ offs, const int* __restrict__ deg,
    const int* __restrict__ elist,
    const __bf16* __restrict__ W2f, const float* __restrict__ b2f,
    float* __restrict__ out)
{
    const int wave = threadIdx.x >> 6;
    const int lane = threadIdx.x & 63;
    const int c = lane & 15, kh = lane >> 4;
    const int rowbase = (blockIdx.x * 4 + wave) * 16;

    int rowA = rowbase + c;
    if (rowA >= NN) rowA = NN - 1;
    const float* xr = X + (size_t)rowA * DD + kh * 8;

    // X half: 4 A-fragments
    bf16x8 afrag[4];
#pragma unroll
    for (int kt = 0; kt < 4; ++kt) {
        f32x4 a0 = *(const f32x4*)(xr + kt * 32);
        f32x4 a1 = *(const f32x4*)(xr + kt * 32 + 4);
        bf16x8 af;
#pragma unroll
        for (int i = 0; i < 4; ++i) { af[i] = (__bf16)a0[i]; af[4 + i] = (__bf16)a1[i]; }
        afrag[kt] = af;
    }

    // gather-mean of T rows for this node (physical/permuted T layout, matches W2f fold)
    float facc[4][8] = {};
    {
        const int beg = offs[rowA];
        const int end = beg + deg[rowA];
        const __bf16* tb = T + (size_t)0;
        for (int e = beg; e < end; ++e) {
            int src = elist[e];
            const __bf16* trow = tb + (size_t)src * DD + kh * 8;
#pragma unroll
            for (int kt = 0; kt < 4; ++kt) {
                bf16x8 v = *(const bf16x8*)(trow + kt * 32);
#pragma unroll
                for (int i = 0; i < 8; ++i) facc[kt][i] += (float)v[i];
            }
        }
    }
    const float inv = 1.0f / fmaxf((float)deg[rowA], 1.0f);

    bf16x8 gfrag[4];
#pragma unroll
    for (int kt = 0; kt < 4; ++kt) {
        bf16x8 af;
#pragma unroll
        for (int i = 0; i < 8; ++i) af[i] = (__bf16)(facc[kt][i] * inv);
        gfrag[kt] = af;
    }

    f32x4 acc[8] = {};
#pragma unroll
    for (int kt = 0; kt < 4; ++kt)
#pragma unroll
        for (int nt = 0; nt < 8; ++nt) {
            bf16x8 bfr = *(const bf16x8*)(W2f + ((size_t)((kt * 8 + nt) * 64 + lane)) * 8);
            acc[nt] = __builtin_amdgcn_mfma_f32_16x16x32_bf16(afrag[kt], bfr, acc[nt], 0, 0, 0);
        }
#pragma unroll
    for (int kt = 0; kt < 4; ++kt)
#pragma unroll
        for (int nt = 0; nt < 8; ++nt) {
            bf16x8 bfr = *(const bf16x8*)(W2f + ((size_t)(((kt + 4) * 8 + nt) * 64 + lane)) * 8);
            acc[nt] = __builtin_amdgcn_mfma_f32_16x16x32_bf16(gfrag[kt], bfr, acc[nt], 0, 0, 0);
        }

    float bias[8];
#pragma unroll
    for (int nt = 0; nt < 8; ++nt) bias[nt] = b2f[nt * 16 + c];

#pragma unroll
    for (int r = 0; r < 4; ++r) {
        int row = rowbase + kh * 4 + r;
        if (row < NN) {
#pragma unroll
            for (int nt = 0; nt < 8; ++nt)
                out[(size_t)row * DD + nt * 16 + c] = gelu_exact(acc[nt][r] + bias[nt]);
        }
    }
}

extern "C" void kernel_launch(void* const* d_in, const int* in_sizes, int n_in,
                              void* d_out, int out_size, void* d_ws, size_t ws_size,
                              hipStream_t stream) {
    const float* node_repr = (const float*)d_in[0];
    const int*   edges     = (const int*)d_in[1];
    const float* g1 = (const float*)d_in[2];
    const float* be1 = (const float*)d_in[3];
    const float* m1 = (const float*)d_in[4];
    const float* v1 = (const float*)d_in[5];
    const float* W1 = (const float*)d_in[6];
    const float* b1 = (const float*)d_in[7];
    const float* g2 = (const float*)d_in[8];
    const float* be2 = (const float*)d_in[9];
    const float* m2 = (const float*)d_in[10];
    const float* v2 = (const float*)d_in[11];
    const float* W2 = (const float*)d_in[12];
    const float* b2 = (const float*)d_in[13];

    char* ws = (char*)d_ws;
    __bf16* W1f = (__bf16*)(ws + W1F_OFF);
    __bf16* W2f = (__bf16*)(ws + W2F_OFF);
    float* b1f = (float*)(ws + B1F_OFF);
    float* b2f = (float*)(ws + B2F_OFF);
    __bf16* T  = (__bf16*)(ws + T_OFF);
    int* deg   = (int*)(ws + DEG_OFF);
    int* offs  = (int*)(ws + OFFS_OFF);
    int* cursor= (int*)(ws + CUR_OFF);
    int* elist = (int*)(ws + ELIST_OFF);
    float* out = (float*)d_out;

    hipMemsetAsync(deg, 0, (size_t)NN * 4, stream);

    hipLaunchKernelGGL(fold_kernel, dim3(1), dim3(256), 0, stream,
                       g1, be1, m1, v1, W1, b1, g2, be2, m2, v2, W2, b2,
                       W1f, W2f, b1f, b2f);

    hipLaunchKernelGGL(hist_kernel, dim3((EE + 255) / 256), dim3(256), 0, stream,
                       edges, deg);

    hipLaunchKernelGGL(ffn1_kernel, dim3((NN + 63) / 64), dim3(256), 0, stream,
                       node_repr, W1f, b1f, T);

    hipLaunchKernelGGL(scan_kernel, dim3(1), dim3(1024), 0, stream,
                       deg, offs, cursor);

    hipLaunchKernelGGL(build_kernel, dim3((EE + 255) / 256), dim3(256), 0, stream,
                       edges, cursor, elist);

    hipLaunchKernelGGL(ffn2_kernel, dim3((NN + 63) / 64), dim3(256), 0, stream,
                       node_repr, T, offs, deg, elist, W2f, b2f, out);
}

// Round 3
// 241.763 us; speedup vs baseline: 9.9670x; 2.0487x over previous
//
#include <hip/hip_runtime.h>

#define NN 100000
#define DD 128
#define EE 640000
#define BN_EPS 1e-3f
#define NBLK 391   // ceil(NN/256)

typedef __bf16 bf16x8 __attribute__((ext_vector_type(8)));
typedef float f32x4 __attribute__((ext_vector_type(4)));

// ---- workspace byte offsets ----
#define W1F_OFF 0u            // 128x128 bf16 frags    = 32768 B
#define W2F_OFF 32768u        // 256x128 bf16 frags    = 65536 B
#define B1F_OFF 98304u        // 128 f32
#define B2F_OFF 98816u        // 128 f32
#define T_OFF   99328u        // NN*128 bf16           = 25,600,000 B
#define DEG_OFF 25699328u     // NN int
#define OFFS_OFF 26099328u    // NN int
#define CUR_OFF 26499328u     // NN int
#define ELIST_OFF 26899328u   // EE int = 2,560,000 B  (end 29,459,328)
#define BSUM_OFF 29459328u    // NBLK int
#define BOFF_OFF 29461376u    // NBLK int

__device__ __forceinline__ float gelu_exact(float x) {
    return 0.5f * x * (1.0f + erff(x * 0.70710678118654752f));
}

// Fold BN into weights; write W in MFMA B-fragment order (bf16).
// B-frag layout for 16x16x32: lane l holds B[k=(l>>4)*8+i][n=(l&15)], per (ktile,ntile).
// linear idx -> i = idx&7, l = (idx>>3)&63, nt = (idx>>9)&7, kt = idx>>12
// agg-half rows of W2 are permuted to match ffn1's permuted t layout:
// physical col' p -> logical col (p&7)*16 + (p>>3)
__global__ void fold_kernel(
    const float* __restrict__ g1, const float* __restrict__ be1,
    const float* __restrict__ m1, const float* __restrict__ v1,
    const float* __restrict__ W1, const float* __restrict__ b1,
    const float* __restrict__ g2, const float* __restrict__ be2,
    const float* __restrict__ m2, const float* __restrict__ v2,
    const float* __restrict__ W2, const float* __restrict__ b2,
    __bf16* __restrict__ W1f, __bf16* __restrict__ W2f,
    float* __restrict__ b1f, float* __restrict__ b2f)
{
    const int tid = threadIdx.x;
    if (tid < 128) {
        float acc = b1[tid];
        for (int k = 0; k < 128; ++k) {
            float s = g1[k] * rsqrtf(v1[k] + BN_EPS);
            float sh = be1[k] - m1[k] * s;
            acc += sh * W1[k * 128 + tid];
        }
        b1f[tid] = acc;
        float acc2 = b2[tid];
        for (int k = 0; k < 256; ++k) {
            float s = g2[k] * rsqrtf(v2[k] + BN_EPS);
            float sh = be2[k] - m2[k] * s;
            acc2 += sh * W2[k * 128 + tid];
        }
        b2f[tid] = acc2;
    }
    for (int idx = tid; idx < 16384; idx += 256) {
        int i = idx & 7, l = (idx >> 3) & 63, nt = (idx >> 9) & 7, kt = idx >> 12;
        int k = kt * 32 + (l >> 4) * 8 + i;
        int n = nt * 16 + (l & 15);
        float s = g1[k] * rsqrtf(v1[k] + BN_EPS);
        W1f[idx] = (__bf16)(s * W1[k * 128 + n]);
    }
    for (int idx = tid; idx < 32768; idx += 256) {
        int i = idx & 7, l = (idx >> 3) & 63, nt = (idx >> 9) & 7, kt = idx >> 12;
        int n = nt * 16 + (l & 15);
        int row;
        if (kt < 4) {
            row = kt * 32 + (l >> 4) * 8 + i;
        } else {
            int q = (kt - 4) * 32 + (l >> 4) * 8 + i;      // physical agg col
            row = 128 + ((q & 7) * 16 + (q >> 3));          // logical W2 row
        }
        float s = g2[row] * rsqrtf(v2[row] + BN_EPS);
        W2f[idx] = (__bf16)(s * W2[row * 128 + n]);
    }
}

// t = gelu(X @ W1f + b1f), stored bf16 with permuted cols: col' = (col&15)*8 + (col>>4)
__global__ __launch_bounds__(256) void ffn1_kernel(
    const float* __restrict__ X, const __bf16* __restrict__ W1f,
    const float* __restrict__ b1f, __bf16* __restrict__ T)
{
    const int wave = threadIdx.x >> 6;
    const int lane = threadIdx.x & 63;
    const int c = lane & 15, kh = lane >> 4;
    const int rowbase = (blockIdx.x * 4 + wave) * 16;

    int rowA = rowbase + c;
    if (rowA >= NN) rowA = NN - 1;
    const float* xr = X + (size_t)rowA * DD + kh * 8;

    bf16x8 afrag[4];
#pragma unroll
    for (int kt = 0; kt < 4; ++kt) {
        f32x4 a0 = *(const f32x4*)(xr + kt * 32);
        f32x4 a1 = *(const f32x4*)(xr + kt * 32 + 4);
        bf16x8 af;
#pragma unroll
        for (int i = 0; i < 4; ++i) { af[i] = (__bf16)a0[i]; af[4 + i] = (__bf16)a1[i]; }
        afrag[kt] = af;
    }

    f32x4 acc[8] = {};
#pragma unroll
    for (int kt = 0; kt < 4; ++kt)
#pragma unroll
        for (int nt = 0; nt < 8; ++nt) {
            bf16x8 bfr = *(const bf16x8*)(W1f + ((size_t)((kt * 8 + nt) * 64 + lane)) * 8);
            acc[nt] = __builtin_amdgcn_mfma_f32_16x16x32_bf16(afrag[kt], bfr, acc[nt], 0, 0, 0);
        }

    float bias[8];
#pragma unroll
    for (int nt = 0; nt < 8; ++nt) bias[nt] = b1f[nt * 16 + c];

#pragma unroll
    for (int r = 0; r < 4; ++r) {
        int row = rowbase + kh * 4 + r;
        if (row < NN) {
            bf16x8 o;
#pragma unroll
            for (int nt = 0; nt < 8; ++nt)
                o[nt] = (__bf16)gelu_exact(acc[nt][r] + bias[nt]);
            *(bf16x8*)(T + (size_t)row * DD + c * 8) = o;
        }
    }
}

// deg[dst]++ over all edges
__global__ __launch_bounds__(256) void hist_kernel(const int* __restrict__ edges,
                                                   int* __restrict__ deg)
{
    int e = blockIdx.x * 256 + threadIdx.x;
    if (e < EE) atomicAdd(&deg[edges[e]], 1);
}

// phase 1: per-block sum of deg
__global__ __launch_bounds__(256) void scan_part_kernel(const int* __restrict__ deg,
                                                        int* __restrict__ bsum)
{
    int i = blockIdx.x * 256 + threadIdx.x;
    int v = (i < NN) ? deg[i] : 0;
#pragma unroll
    for (int off = 32; off > 0; off >>= 1) v += __shfl_down(v, off);
    __shared__ int ws[4];
    if ((threadIdx.x & 63) == 0) ws[threadIdx.x >> 6] = v;
    __syncthreads();
    if (threadIdx.x == 0) bsum[blockIdx.x] = ws[0] + ws[1] + ws[2] + ws[3];
}

// phase 2: single-block exclusive scan of NBLK block sums
__global__ __launch_bounds__(512) void scan_top_kernel(const int* __restrict__ bsum,
                                                       int* __restrict__ boff)
{
    __shared__ int s[512];
    const int t = threadIdx.x;
    int v = (t < NBLK) ? bsum[t] : 0;
    s[t] = v;
    __syncthreads();
    for (int off = 1; off < 512; off <<= 1) {
        int tmp = (t >= off) ? s[t - off] : 0;
        __syncthreads();
        s[t] += tmp;
        __syncthreads();
    }
    if (t < NBLK) boff[t] = s[t] - v;
}

// phase 3: per-block exclusive scan + block offset -> offs, cursor
__global__ __launch_bounds__(256) void scan_final_kernel(const int* __restrict__ deg,
                                                         const int* __restrict__ boff,
                                                         int* __restrict__ offs,
                                                         int* __restrict__ cursor)
{
    __shared__ int s[256];
    const int t = threadIdx.x;
    int i = blockIdx.x * 256 + t;
    int v = (i < NN) ? deg[i] : 0;
    s[t] = v;
    __syncthreads();
    for (int off = 1; off < 256; off <<= 1) {
        int tmp = (t >= off) ? s[t - off] : 0;
        __syncthreads();
        s[t] += tmp;
        __syncthreads();
    }
    int ex = s[t] - v + boff[blockIdx.x];
    if (i < NN) { offs[i] = ex; cursor[i] = ex; }
}

// CSR edge list: elist[offs[dst] ...] = src
__global__ __launch_bounds__(256) void build_kernel(const int* __restrict__ edges,
                                                    int* __restrict__ cursor,
                                                    int* __restrict__ elist)
{
    int e = blockIdx.x * 256 + threadIdx.x;
    if (e >= EE) return;
    int dst = edges[e];
    int src = edges[EE + e];
    int pos = atomicAdd(&cursor[dst], 1);
    elist[pos] = src;
}

// out = gelu([X, mean_gather(T)] @ W2f + b2f); aggregation fused via CSR gather
__global__ __launch_bounds__(256) void ffn2_kernel(
    const float* __restrict__ X, const __bf16* __restrict__ T,
    const int* __restrict__ offs, const int* __restrict__ deg,
    const int* __restrict__ elist,
    const __bf16* __restrict__ W2f, const float* __restrict__ b2f,
    float* __restrict__ out)
{
    const int wave = threadIdx.x >> 6;
    const int lane = threadIdx.x & 63;
    const int c = lane & 15, kh = lane >> 4;
    const int rowbase = (blockIdx.x * 4 + wave) * 16;

    int rowA = rowbase + c;
    if (rowA >= NN) rowA = NN - 1;
    const float* xr = X + (size_t)rowA * DD + kh * 8;

    // X half: 4 A-fragments
    bf16x8 afrag[4];
#pragma unroll
    for (int kt = 0; kt < 4; ++kt) {
        f32x4 a0 = *(const f32x4*)(xr + kt * 32);
        f32x4 a1 = *(const f32x4*)(xr + kt * 32 + 4);
        bf16x8 af;
#pragma unroll
        for (int i = 0; i < 4; ++i) { af[i] = (__bf16)a0[i]; af[4 + i] = (__bf16)a1[i]; }
        afrag[kt] = af;
    }

    // gather-mean of T rows for this node (physical/permuted T layout, matches W2f fold)
    float facc[4][8] = {};
    {
        const int beg = offs[rowA];
        const int end = beg + deg[rowA];
        for (int e = beg; e < end; ++e) {
            int src = elist[e];
            const __bf16* trow = T + (size_t)src * DD + kh * 8;
#pragma unroll
            for (int kt = 0; kt < 4; ++kt) {
                bf16x8 v = *(const bf16x8*)(trow + kt * 32);
#pragma unroll
                for (int i = 0; i < 8; ++i) facc[kt][i] += (float)v[i];
            }
        }
    }
    const float inv = 1.0f / fmaxf((float)deg[rowA], 1.0f);

    bf16x8 gfrag[4];
#pragma unroll
    for (int kt = 0; kt < 4; ++kt) {
        bf16x8 af;
#pragma unroll
        for (int i = 0; i < 8; ++i) af[i] = (__bf16)(facc[kt][i] * inv);
        gfrag[kt] = af;
    }

    f32x4 acc[8] = {};
#pragma unroll
    for (int kt = 0; kt < 4; ++kt)
#pragma unroll
        for (int nt = 0; nt < 8; ++nt) {
            bf16x8 bfr = *(const bf16x8*)(W2f + ((size_t)((kt * 8 + nt) * 64 + lane)) * 8);
            acc[nt] = __builtin_amdgcn_mfma_f32_16x16x32_bf16(afrag[kt], bfr, acc[nt], 0, 0, 0);
        }
#pragma unroll
    for (int kt = 0; kt < 4; ++kt)
#pragma unroll
        for (int nt = 0; nt < 8; ++nt) {
            bf16x8 bfr = *(const bf16x8*)(W2f + ((size_t)(((kt + 4) * 8 + nt) * 64 + lane)) * 8);
            acc[nt] = __builtin_amdgcn_mfma_f32_16x16x32_bf16(gfrag[kt], bfr, acc[nt], 0, 0, 0);
        }

    float bias[8];
#pragma unroll
    for (int nt = 0; nt < 8; ++nt) bias[nt] = b2f[nt * 16 + c];

#pragma unroll
    for (int r = 0; r < 4; ++r) {
        int row = rowbase + kh * 4 + r;
        if (row < NN) {
#pragma unroll
            for (int nt = 0; nt < 8; ++nt)
                out[(size_t)row * DD + nt * 16 + c] = gelu_exact(acc[nt][r] + bias[nt]);
        }
    }
}

extern "C" void kernel_launch(void* const* d_in, const int* in_sizes, int n_in,
                              void* d_out, int out_size, void* d_ws, size_t ws_size,
                              hipStream_t stream) {
    const float* node_repr = (const float*)d_in[0];
    const int*   edges     = (const int*)d_in[1];
    const float* g1 = (const float*)d_in[2];
    const float* be1 = (const float*)d_in[3];
    const float* m1 = (const float*)d_in[4];
    const float* v1 = (const float*)d_in[5];
    const float* W1 = (const float*)d_in[6];
    const float* b1 = (const float*)d_in[7];
    const float* g2 = (const float*)d_in[8];
    const float* be2 = (const float*)d_in[9];
    const float* m2 = (const float*)d_in[10];
    const float* v2 = (const float*)d_in[11];
    const float* W2 = (const float*)d_in[12];
    const float* b2 = (const float*)d_in[13];

    char* ws = (char*)d_ws;
    __bf16* W1f = (__bf16*)(ws + W1F_OFF);
    __bf16* W2f = (__bf16*)(ws + W2F_OFF);
    float* b1f = (float*)(ws + B1F_OFF);
    float* b2f = (float*)(ws + B2F_OFF);
    __bf16* T  = (__bf16*)(ws + T_OFF);
    int* deg   = (int*)(ws + DEG_OFF);
    int* offs  = (int*)(ws + OFFS_OFF);
    int* cursor= (int*)(ws + CUR_OFF);
    int* elist = (int*)(ws + ELIST_OFF);
    int* bsum  = (int*)(ws + BSUM_OFF);
    int* boff  = (int*)(ws + BOFF_OFF);
    float* out = (float*)d_out;

    hipMemsetAsync(deg, 0, (size_t)NN * 4, stream);

    hipLaunchKernelGGL(fold_kernel, dim3(1), dim3(256), 0, stream,
                       g1, be1, m1, v1, W1, b1, g2, be2, m2, v2, W2, b2,
                       W1f, W2f, b1f, b2f);

    hipLaunchKernelGGL(hist_kernel, dim3((EE + 255) / 256), dim3(256), 0, stream,
                       edges, deg);

    hipLaunchKernelGGL(ffn1_kernel, dim3((NN + 63) / 64), dim3(256), 0, stream,
                       node_repr, W1f, b1f, T);

    hipLaunchKernelGGL(scan_part_kernel, dim3(NBLK), dim3(256), 0, stream, deg, bsum);
    hipLaunchKernelGGL(scan_top_kernel, dim3(1), dim3(512), 0, stream, bsum, boff);
    hipLaunchKernelGGL(scan_final_kernel, dim3(NBLK), dim3(256), 0, stream, deg, boff, offs, cursor);

    hipLaunchKernelGGL(build_kernel, dim3((EE + 255) / 256), dim3(256), 0, stream,
                       edges, cursor, elist);

    hipLaunchKernelGGL(ffn2_kernel, dim3((NN + 63) / 64), dim3(256), 0, stream,
                       node_repr, T, offs, deg, elist, W2f, b2f, out);
}

// Round 4
// 178.522 us; speedup vs baseline: 13.4977x; 1.3542x over previous
//
#include <hip/hip_runtime.h>

#define NN 100000
#define DD 128
#define EE 640000
#define BN_EPS 1e-3f
#define NBLK 391   // ceil(NN/256)

typedef __bf16 bf16x8 __attribute__((ext_vector_type(8)));
typedef float f32x4 __attribute__((ext_vector_type(4)));

// ---- workspace byte offsets ----
#define W1F_OFF 0u            // 128x128 bf16 frags    = 32768 B
#define W2F_OFF 32768u        // 256x128 bf16 frags    = 65536 B
#define B1F_OFF 98304u        // 128 f32
#define B2F_OFF 98816u        // 128 f32
#define T_OFF   99328u        // NN*128 bf16           = 25,600,000 B
#define DEG_OFF 25699328u     // NN int
#define OFFS_OFF 26099328u    // NN int
#define CUR_OFF 26499328u     // NN int
#define ELIST_OFF 26899328u   // EE int = 2,560,000 B
#define BSUM_OFF 29459328u    // NBLK int
#define BOFF_OFF 29461376u    // NBLK int
#define AGG_OFF 29464576u     // NN*128 bf16 = 25,600,000 B (end ~55.1 MB)

__device__ __forceinline__ float gelu_exact(float x) {
    return 0.5f * x * (1.0f + erff(x * 0.70710678118654752f));
}

// bias fold: one wave per output column (256 waves total)
__global__ __launch_bounds__(256) void fold_bias_kernel(
    const float* __restrict__ g1, const float* __restrict__ be1,
    const float* __restrict__ m1, const float* __restrict__ v1,
    const float* __restrict__ W1, const float* __restrict__ b1,
    const float* __restrict__ g2, const float* __restrict__ be2,
    const float* __restrict__ m2, const float* __restrict__ v2,
    const float* __restrict__ W2, const float* __restrict__ b2,
    float* __restrict__ b1f, float* __restrict__ b2f)
{
    const int w = (blockIdx.x * 256 + threadIdx.x) >> 6;   // 0..255
    const int lane = threadIdx.x & 63;
    if (w < 128) {
        float acc = 0.f;
        for (int k = lane; k < 128; k += 64) {
            float s = g1[k] * rsqrtf(v1[k] + BN_EPS);
            float sh = be1[k] - m1[k] * s;
            acc += sh * W1[k * 128 + w];
        }
#pragma unroll
        for (int off = 32; off > 0; off >>= 1) acc += __shfl_down(acc, off);
        if (lane == 0) b1f[w] = acc + b1[w];
    } else {
        const int n = w - 128;
        float acc = 0.f;
        for (int k = lane; k < 256; k += 64) {
            float s = g2[k] * rsqrtf(v2[k] + BN_EPS);
            float sh = be2[k] - m2[k] * s;
            acc += sh * W2[k * 128 + n];
        }
#pragma unroll
        for (int off = 32; off > 0; off >>= 1) acc += __shfl_down(acc, off);
        if (lane == 0) b2f[n] = acc + b2[n];
    }
}

// weight fold into MFMA B-fragment order; grid covers 16384+32768 elements exactly.
// B-frag: lane l holds B[k=(l>>4)*8+i][n=(l&15)] per (kt,nt).
// agg-half rows of W2 permuted: physical col p -> logical col (p&7)*16 + (p>>3)
__global__ __launch_bounds__(256) void fold_w_kernel(
    const float* __restrict__ g1, const float* __restrict__ v1,
    const float* __restrict__ W1,
    const float* __restrict__ g2, const float* __restrict__ v2,
    const float* __restrict__ W2,
    __bf16* __restrict__ W1f, __bf16* __restrict__ W2f)
{
    int tid = blockIdx.x * 256 + threadIdx.x;
    if (tid < 16384) {
        int idx = tid;
        int i = idx & 7, l = (idx >> 3) & 63, nt = (idx >> 9) & 7, kt = idx >> 12;
        int k = kt * 32 + (l >> 4) * 8 + i;
        int n = nt * 16 + (l & 15);
        float s = g1[k] * rsqrtf(v1[k] + BN_EPS);
        W1f[idx] = (__bf16)(s * W1[k * 128 + n]);
    } else {
        int idx = tid - 16384;
        int i = idx & 7, l = (idx >> 3) & 63, nt = (idx >> 9) & 7, kt = idx >> 12;
        int n = nt * 16 + (l & 15);
        int row;
        if (kt < 4) {
            row = kt * 32 + (l >> 4) * 8 + i;
        } else {
            int q = (kt - 4) * 32 + (l >> 4) * 8 + i;      // physical agg col
            row = 128 + ((q & 7) * 16 + (q >> 3));          // logical W2 row
        }
        float s = g2[row] * rsqrtf(v2[row] + BN_EPS);
        W2f[idx] = (__bf16)(s * W2[row * 128 + n]);
    }
}

// t = gelu(X @ W1f + b1f), stored bf16 with permuted cols: col' = (col&15)*8 + (col>>4)
__global__ __launch_bounds__(256) void ffn1_kernel(
    const float* __restrict__ X, const __bf16* __restrict__ W1f,
    const float* __restrict__ b1f, __bf16* __restrict__ T)
{
    const int wave = threadIdx.x >> 6;
    const int lane = threadIdx.x & 63;
    const int c = lane & 15, kh = lane >> 4;
    const int rowbase = (blockIdx.x * 4 + wave) * 16;

    int rowA = rowbase + c;
    if (rowA >= NN) rowA = NN - 1;
    const float* xr = X + (size_t)rowA * DD + kh * 8;

    bf16x8 afrag[4];
#pragma unroll
    for (int kt = 0; kt < 4; ++kt) {
        f32x4 a0 = *(const f32x4*)(xr + kt * 32);
        f32x4 a1 = *(const f32x4*)(xr + kt * 32 + 4);
        bf16x8 af;
#pragma unroll
        for (int i = 0; i < 4; ++i) { af[i] = (__bf16)a0[i]; af[4 + i] = (__bf16)a1[i]; }
        afrag[kt] = af;
    }

    f32x4 acc[8] = {};
#pragma unroll
    for (int kt = 0; kt < 4; ++kt)
#pragma unroll
        for (int nt = 0; nt < 8; ++nt) {
            bf16x8 bfr = *(const bf16x8*)(W1f + ((size_t)((kt * 8 + nt) * 64 + lane)) * 8);
            acc[nt] = __builtin_amdgcn_mfma_f32_16x16x32_bf16(afrag[kt], bfr, acc[nt], 0, 0, 0);
        }

    float bias[8];
#pragma unroll
    for (int nt = 0; nt < 8; ++nt) bias[nt] = b1f[nt * 16 + c];

#pragma unroll
    for (int r = 0; r < 4; ++r) {
        int row = rowbase + kh * 4 + r;
        if (row < NN) {
            bf16x8 o;
#pragma unroll
            for (int nt = 0; nt < 8; ++nt)
                o[nt] = (__bf16)gelu_exact(acc[nt][r] + bias[nt]);
            *(bf16x8*)(T + (size_t)row * DD + c * 8) = o;
        }
    }
}

// deg[dst]++ over all edges
__global__ __launch_bounds__(256) void hist_kernel(const int* __restrict__ edges,
                                                   int* __restrict__ deg)
{
    int e = blockIdx.x * 256 + threadIdx.x;
    if (e < EE) atomicAdd(&deg[edges[e]], 1);
}

// phase 1: per-block sum of deg
__global__ __launch_bounds__(256) void scan_part_kernel(const int* __restrict__ deg,
                                                        int* __restrict__ bsum)
{
    int i = blockIdx.x * 256 + threadIdx.x;
    int v = (i < NN) ? deg[i] : 0;
#pragma unroll
    for (int off = 32; off > 0; off >>= 1) v += __shfl_down(v, off);
    __shared__ int ws[4];
    if ((threadIdx.x & 63) == 0) ws[threadIdx.x >> 6] = v;
    __syncthreads();
    if (threadIdx.x == 0) bsum[blockIdx.x] = ws[0] + ws[1] + ws[2] + ws[3];
}

// phase 2: single-block exclusive scan of NBLK block sums
__global__ __launch_bounds__(512) void scan_top_kernel(const int* __restrict__ bsum,
                                                       int* __restrict__ boff)
{
    __shared__ int s[512];
    const int t = threadIdx.x;
    int v = (t < NBLK) ? bsum[t] : 0;
    s[t] = v;
    __syncthreads();
    for (int off = 1; off < 512; off <<= 1) {
        int tmp = (t >= off) ? s[t - off] : 0;
        __syncthreads();
        s[t] += tmp;
        __syncthreads();
    }
    if (t < NBLK) boff[t] = s[t] - v;
}

// phase 3: per-block exclusive scan + block offset -> offs, cursor
__global__ __launch_bounds__(256) void scan_final_kernel(const int* __restrict__ deg,
                                                         const int* __restrict__ boff,
                                                         int* __restrict__ offs,
                                                         int* __restrict__ cursor)
{
    __shared__ int s[256];
    const int t = threadIdx.x;
    int i = blockIdx.x * 256 + t;
    int v = (i < NN) ? deg[i] : 0;
    s[t] = v;
    __syncthreads();
    for (int off = 1; off < 256; off <<= 1) {
        int tmp = (t >= off) ? s[t - off] : 0;
        __syncthreads();
        s[t] += tmp;
        __syncthreads();
    }
    int ex = s[t] - v + boff[blockIdx.x];
    if (i < NN) { offs[i] = ex; cursor[i] = ex; }
}

// CSR edge list: elist[offs[dst] ...] = src
__global__ __launch_bounds__(256) void build_kernel(const int* __restrict__ edges,
                                                    int* __restrict__ cursor,
                                                    int* __restrict__ elist)
{
    int e = blockIdx.x * 256 + threadIdx.x;
    if (e >= EE) return;
    int dst = edges[e];
    int src = edges[EE + e];
    int pos = atomicAdd(&cursor[dst], 1);
    elist[pos] = src;
}

// gather-mean: Agg[node] = mean of T[src] rows (physical/permuted col layout kept).
// thread <-> (node, 8-col slice); low VGPR -> max occupancy for latency hiding.
__global__ __launch_bounds__(256) void agg_kernel(
    const __bf16* __restrict__ T, const int* __restrict__ offs,
    const int* __restrict__ deg, const int* __restrict__ elist,
    __bf16* __restrict__ Agg)
{
    int t = blockIdx.x * 256 + threadIdx.x;
    int node = t >> 4, j = t & 15;
    if (node >= NN) return;
    const int beg = offs[node];
    const int d = deg[node];
    const int end = beg + d;
    float acc[8] = {};
    int e = beg;
    for (; e + 1 < end; e += 2) {
        int s0 = elist[e], s1 = elist[e + 1];
        bf16x8 v0 = *(const bf16x8*)(T + (size_t)s0 * DD + j * 8);
        bf16x8 v1 = *(const bf16x8*)(T + (size_t)s1 * DD + j * 8);
#pragma unroll
        for (int i = 0; i < 8; ++i) acc[i] += (float)v0[i] + (float)v1[i];
    }
    if (e < end) {
        int s0 = elist[e];
        bf16x8 v0 = *(const bf16x8*)(T + (size_t)s0 * DD + j * 8);
#pragma unroll
        for (int i = 0; i < 8; ++i) acc[i] += (float)v0[i];
    }
    const float inv = 1.0f / fmaxf((float)d, 1.0f);
    bf16x8 o;
#pragma unroll
    for (int i = 0; i < 8; ++i) o[i] = (__bf16)(acc[i] * inv);
    *(bf16x8*)(Agg + (size_t)node * DD + j * 8) = o;
}

// out = gelu([X, Agg] @ W2f + b2f)  — pure streaming GEMM now
__global__ __launch_bounds__(256) void ffn2_kernel(
    const float* __restrict__ X, const __bf16* __restrict__ Agg,
    const __bf16* __restrict__ W2f, const float* __restrict__ b2f,
    float* __restrict__ out)
{
    const int wave = threadIdx.x >> 6;
    const int lane = threadIdx.x & 63;
    const int c = lane & 15, kh = lane >> 4;
    const int rowbase = (blockIdx.x * 4 + wave) * 16;

    int rowA = rowbase + c;
    if (rowA >= NN) rowA = NN - 1;
    const float* xr = X + (size_t)rowA * DD + kh * 8;
    const __bf16* ar = Agg + (size_t)rowA * DD + kh * 8;

    bf16x8 afrag[4], gfrag[4];
#pragma unroll
    for (int kt = 0; kt < 4; ++kt) {
        f32x4 a0 = *(const f32x4*)(xr + kt * 32);
        f32x4 a1 = *(const f32x4*)(xr + kt * 32 + 4);
        bf16x8 af;
#pragma unroll
        for (int i = 0; i < 4; ++i) { af[i] = (__bf16)a0[i]; af[4 + i] = (__bf16)a1[i]; }
        afrag[kt] = af;
        gfrag[kt] = *(const bf16x8*)(ar + kt * 32);
    }

    f32x4 acc[8] = {};
#pragma unroll
    for (int kt = 0; kt < 4; ++kt)
#pragma unroll
        for (int nt = 0; nt < 8; ++nt) {
            bf16x8 bfr = *(const bf16x8*)(W2f + ((size_t)((kt * 8 + nt) * 64 + lane)) * 8);
            acc[nt] = __builtin_amdgcn_mfma_f32_16x16x32_bf16(afrag[kt], bfr, acc[nt], 0, 0, 0);
        }
#pragma unroll
    for (int kt = 0; kt < 4; ++kt)
#pragma unroll
        for (int nt = 0; nt < 8; ++nt) {
            bf16x8 bfr = *(const bf16x8*)(W2f + ((size_t)(((kt + 4) * 8 + nt) * 64 + lane)) * 8);
            acc[nt] = __builtin_amdgcn_mfma_f32_16x16x32_bf16(gfrag[kt], bfr, acc[nt], 0, 0, 0);
        }

    float bias[8];
#pragma unroll
    for (int nt = 0; nt < 8; ++nt) bias[nt] = b2f[nt * 16 + c];

#pragma unroll
    for (int r = 0; r < 4; ++r) {
        int row = rowbase + kh * 4 + r;
        if (row < NN) {
#pragma unroll
            for (int nt = 0; nt < 8; ++nt)
                out[(size_t)row * DD + nt * 16 + c] = gelu_exact(acc[nt][r] + bias[nt]);
        }
    }
}

extern "C" void kernel_launch(void* const* d_in, const int* in_sizes, int n_in,
                              void* d_out, int out_size, void* d_ws, size_t ws_size,
                              hipStream_t stream) {
    const float* node_repr = (const float*)d_in[0];
    const int*   edges     = (const int*)d_in[1];
    const float* g1 = (const float*)d_in[2];
    const float* be1 = (const float*)d_in[3];
    const float* m1 = (const float*)d_in[4];
    const float* v1 = (const float*)d_in[5];
    const float* W1 = (const float*)d_in[6];
    const float* b1 = (const float*)d_in[7];
    const float* g2 = (const float*)d_in[8];
    const float* be2 = (const float*)d_in[9];
    const float* m2 = (const float*)d_in[10];
    const float* v2 = (const float*)d_in[11];
    const float* W2 = (const float*)d_in[12];
    const float* b2 = (const float*)d_in[13];

    char* ws = (char*)d_ws;
    __bf16* W1f = (__bf16*)(ws + W1F_OFF);
    __bf16* W2f = (__bf16*)(ws + W2F_OFF);
    float* b1f = (float*)(ws + B1F_OFF);
    float* b2f = (float*)(ws + B2F_OFF);
    __bf16* T  = (__bf16*)(ws + T_OFF);
    int* deg   = (int*)(ws + DEG_OFF);
    int* offs  = (int*)(ws + OFFS_OFF);
    int* cursor= (int*)(ws + CUR_OFF);
    int* elist = (int*)(ws + ELIST_OFF);
    int* bsum  = (int*)(ws + BSUM_OFF);
    int* boff  = (int*)(ws + BOFF_OFF);
    __bf16* Agg = (__bf16*)(ws + AGG_OFF);
    float* out = (float*)d_out;

    hipMemsetAsync(deg, 0, (size_t)NN * 4, stream);

    hipLaunchKernelGGL(fold_bias_kernel, dim3(64), dim3(256), 0, stream,
                       g1, be1, m1, v1, W1, b1, g2, be2, m2, v2, W2, b2, b1f, b2f);
    hipLaunchKernelGGL(fold_w_kernel, dim3(192), dim3(256), 0, stream,
                       g1, v1, W1, g2, v2, W2, W1f, W2f);

    hipLaunchKernelGGL(hist_kernel, dim3((EE + 255) / 256), dim3(256), 0, stream,
                       edges, deg);

    hipLaunchKernelGGL(ffn1_kernel, dim3((NN + 63) / 64), dim3(256), 0, stream,
                       node_repr, W1f, b1f, T);

    hipLaunchKernelGGL(scan_part_kernel, dim3(NBLK), dim3(256), 0, stream, deg, bsum);
    hipLaunchKernelGGL(scan_top_kernel, dim3(1), dim3(512), 0, stream, bsum, boff);
    hipLaunchKernelGGL(scan_final_kernel, dim3(NBLK), dim3(256), 0, stream, deg, boff, offs, cursor);

    hipLaunchKernelGGL(build_kernel, dim3((EE + 255) / 256), dim3(256), 0, stream,
                       edges, cursor, elist);

    hipLaunchKernelGGL(agg_kernel, dim3((NN * 16 + 255) / 256), dim3(256), 0, stream,
                       T, offs, deg, elist, Agg);

    hipLaunchKernelGGL(ffn2_kernel, dim3((NN + 63) / 64), dim3(256), 0, stream,
                       node_repr, Agg, W2f, b2f, out);
}